// Round 7
// baseline (409.935 us; speedup 1.0000x reference)
//
#include <hip/hip_runtime.h>
#include <hip/hip_bf16.h>
#include <cstdint>

#define NNODES 20000
#define NEDGES 640000
#define ETOT   (NEDGES + NNODES)
#define NGROUP 64
#define HC     256
#define DOUT   32

typedef short bf16x8 __attribute__((ext_vector_type(8)));
typedef short s16x8  __attribute__((ext_vector_type(8)));
typedef float f32x4  __attribute__((ext_vector_type(4)));
typedef float f32x8  __attribute__((ext_vector_type(8)));
typedef float f32x2  __attribute__((ext_vector_type(2)));

__device__ __forceinline__ float b2f(__hip_bfloat16 v) { return __bfloat162float(v); }
__device__ __forceinline__ float bs2f(short v) {
    union { unsigned int u; float f; } c; c.u = ((unsigned int)(unsigned short)v) << 16; return c.f;
}
__device__ __forceinline__ short f2bs(float v) {
    __hip_bfloat16 b = __float2bfloat16(v);
    union { __hip_bfloat16 b; short s; } u; u.b = b; return u.s;
}
__device__ __forceinline__ float ldf(const void* __restrict__ p, size_t i, int bf) {
    return bf ? __bfloat162float(((const __hip_bfloat16*)p)[i]) : ((const float*)p)[i];
}
__device__ __forceinline__ int ld_idx(const int* __restrict__ p, size_t i, int f64) {
    return f64 ? p[2 * i] : p[i];
}

// ---- inline wave probes (call with FULL wave, before any divergence) ----
// int64 detect on edge_index: odd words are high-halves (int64) or random ids (int32)
__device__ __forceinline__ int probe_i64(const int* __restrict__ ei) {
    int l = threadIdx.x & 63;
    unsigned long long b = __ballot(ei[2 * l + 1] == 0);
    return (__popcll(b) > 48) ? 1 : 0;
}
// bf16 detect on a float array: word bit14 = fp32 mantissa (~50%) vs upper-bf16 exp MSB (~0 for |v|<2)
__device__ __forceinline__ int probe_bf(const unsigned int* __restrict__ xw) {
    int l = threadIdx.x & 63;
    unsigned long long b = __ballot((xw[l] >> 14) & 1);
    return (__popcll(b) < 16) ? 1 : 0;
}

// ---------------- CSR build over dst ----------------
__global__ void k_hist(const int* __restrict__ ei, int* __restrict__ deg) {
    int f = probe_i64(ei);
    int i = blockIdx.x * blockDim.x + threadIdx.x;
    if (i >= ETOT) return;
    int d = (i < NEDGES) ? ld_idx(ei, (size_t)NEDGES + i, f) : (i - NEDGES);
    atomicAdd(&deg[d], 1);
}

__global__ void k_scan(const int* __restrict__ deg, int* __restrict__ off, int* __restrict__ cur) {
    __shared__ unsigned short dl[NNODES];  // 40 KB
    __shared__ int wtot[8];
    int t = threadIdx.x;
    for (int i = t; i < NNODES; i += 512) dl[i] = (unsigned short)deg[i];
    __syncthreads();
    const int chunk = (NNODES + 511) / 512;  // 40
    int s = t * chunk, e = min(s + chunk, NNODES);
    int sum = 0;
    for (int i = s; i < e; i++) sum += dl[i];
    int lane = t & 63, wv = t >> 6;
    int v = sum;
#pragma unroll
    for (int o = 1; o < 64; o <<= 1) {
        int u = __shfl_up(v, o);
        if (lane >= o) v += u;
    }
    if (lane == 63) wtot[wv] = v;
    __syncthreads();
    int woff = 0;
    for (int i = 0; i < wv; i++) woff += wtot[i];
    int run = woff + v - sum;
    for (int i = s; i < e; i++) { off[i] = run; cur[i] = run; run += dl[i]; }
    if (t == 511) off[NNODES] = ETOT;
}

__global__ void k_scatter(const int* __restrict__ ei, int* __restrict__ cur,
                          int* __restrict__ csr) {
    int f = probe_i64(ei);
    int i = blockIdx.x * blockDim.x + threadIdx.x;
    if (i >= ETOT) return;
    int s, d;
    if (i < NEDGES) { s = ld_idx(ei, i, f); d = ld_idx(ei, (size_t)NEDGES + i, f); }
    else            { s = d = i - NEDGES; }
    int pos = atomicAdd(&cur[d], 1);
    csr[pos] = s;
}

// ---------------- both weight transposes ----------------
__global__ void k_wt(const void* __restrict__ W1, const void* __restrict__ W2,
                     __hip_bfloat16* __restrict__ Wt1, __hip_bfloat16* __restrict__ Wt2) {
    int bf = probe_bf((const unsigned int*)W1);
    int i = blockIdx.x * 256 + threadIdx.x;  // 131072
    int which = i >> 16;
    int j = i & 65535;
    int k = j >> 8, n = j & 255;
    const void* W = which ? W2 : W1;
    __hip_bfloat16* Wt = which ? Wt2 : Wt1;
    Wt[(size_t)n * 256 + k] = __float2bfloat16(ldf(W, (size_t)k * 256 + n, bf));
}

// ---------------- GEMM (64 rows/block, 8 waves of 512) + fused scores ----------------
// wave w: rows r0 = blk*64 + (w&3)*16, cols ch*128.. (ch = w>>2). acc[8] -> 32 VGPR, spill-safe.
// A frag: lane holds A[m=lane&15][k=(lane>>4)*8+j]; B mirrors with n=lane&15.
// D frag: col=lane&15, row=(lane>>4)*4+reg (m89/m91-verified).
__global__ __launch_bounds__(512) void k_gemm(const void* __restrict__ A,
                                              const __hip_bfloat16* __restrict__ Bt,
                                              __hip_bfloat16* __restrict__ Hout,
                                              const void* __restrict__ a_src,
                                              const void* __restrict__ a_dst,
                                              float* __restrict__ es4, float* __restrict__ ed4,
                                              const void* __restrict__ xprobe, int force_bf) {
    int bf   = probe_bf((const unsigned int*)xprobe);
    int abf  = force_bf | bf;
    int w    = threadIdx.x >> 6;
    int lane = threadIdx.x & 63;
    int mr   = lane & 15;
    int quad = lane >> 4;
    int ch   = w >> 2;                       // col half: heads 2ch,2ch+1
    int r0   = blockIdx.x * 64 + (w & 3) * 16;
    f32x4 acc[8];
#pragma unroll
    for (int j = 0; j < 8; j++) acc[j] = (f32x4){0.f, 0.f, 0.f, 0.f};
    size_t rowoff = (size_t)min(r0 + mr, NNODES - 1) * HC;
    for (int kk = 0; kk < HC; kk += 32) {
        bf16x8 a;
        if (abf) {
            a = *reinterpret_cast<const bf16x8*>((const __hip_bfloat16*)A + rowoff + kk + quad * 8);
        } else {
            const float* af = (const float*)A + rowoff + kk + quad * 8;
            f32x4 lo = *reinterpret_cast<const f32x4*>(af);
            f32x4 hi = *reinterpret_cast<const f32x4*>(af + 4);
#pragma unroll
            for (int ii = 0; ii < 4; ii++) { a[ii] = f2bs(lo[ii]); a[ii + 4] = f2bs(hi[ii]); }
        }
#pragma unroll
        for (int j = 0; j < 8; j++) {
            bf16x8 b = *reinterpret_cast<const bf16x8*>(
                Bt + (size_t)(ch * 128 + j * 16 + mr) * HC + kk + quad * 8);
            acc[j] = __builtin_amdgcn_mfma_f32_16x16x32_bf16(a, b, acc[j], 0, 0, 0);
        }
    }
    // store H (bf16), guarded
#pragma unroll
    for (int j = 0; j < 8; j++)
#pragma unroll
        for (int r = 0; r < 4; r++) {
            int row = r0 + quad * 4 + r;
            if (row < NNODES)
                Hout[(size_t)row * HC + ch * 128 + j * 16 + mr] = __float2bfloat16(acc[j][r]);
        }
    // fused scores for this wave's 2 heads
    float ps[2][4], pd[2][4];
#pragma unroll
    for (int h = 0; h < 2; h++)
#pragma unroll
        for (int r = 0; r < 4; r++) { ps[h][r] = 0.f; pd[h][r] = 0.f; }
#pragma unroll
    for (int j = 0; j < 8; j++) {
        int h = j >> 2;
        size_t col = (size_t)ch * 128 + j * 16 + mr;
        float asv = ldf(a_src, col, bf);
        float adv = ldf(a_dst, col, bf);
#pragma unroll
        for (int r = 0; r < 4; r++) {
            ps[h][r] = fmaf(acc[j][r], asv, ps[h][r]);
            pd[h][r] = fmaf(acc[j][r], adv, pd[h][r]);
        }
    }
#pragma unroll
    for (int o = 1; o < 16; o <<= 1)
#pragma unroll
        for (int h = 0; h < 2; h++)
#pragma unroll
            for (int r = 0; r < 4; r++) {
                ps[h][r] += __shfl_xor(ps[h][r], o);
                pd[h][r] += __shfl_xor(pd[h][r], o);
            }
    if (mr == 0)
#pragma unroll
        for (int r = 0; r < 4; r++) {
            int row = r0 + quad * 4 + r;
            if (row < NNODES) {
                *reinterpret_cast<f32x2*>(es4 + (size_t)row * 4 + ch * 2) = (f32x2){ps[0][r], ps[1][r]};
                *reinterpret_cast<f32x2*>(ed4 + (size_t)row * 4 + ch * 2) = (f32x2){pd[0][r], pd[1][r]};
            }
        }
}

// ---------------- wave-per-node softmax + aggregation, paired-edge 16B gathers ----------------
// softmax phase: lane = edge (chunk of 64). gather phase: lane covers 8 features of half a row;
// two edges per iteration (half = lane>>5), merged at the end via shfl_xor(32).
__global__ __launch_bounds__(256) void k_agg(const __hip_bfloat16* __restrict__ Hb,
                                             const float* __restrict__ es4, const float* __restrict__ ed4,
                                             const void* __restrict__ bias,
                                             const int* __restrict__ off, const int* __restrict__ csr,
                                             const void* __restrict__ xprobe,
                                             __hip_bfloat16* __restrict__ out) {
    __shared__ float p_lds[4][256];
    __shared__ int   s_lds[4][64];
    int bf = probe_bf((const unsigned int*)xprobe);
    int wv = threadIdx.x >> 6;
    int l  = threadIdx.x & 63;
    int half = l >> 5;           // which edge of the pair
    int fl   = l & 31;           // feature group: feats fl*8..fl*8+7
    int hd8  = fl >> 3;          // head of that feature group
    int wid  = blockIdx.x * 4 + wv;   // 5000 waves, persistent over 4 nodes each
    for (int n = wid; n < NNODES; n += 5000) {
        int base = off[n], deg = off[n + 1] - base;
        f32x4 edv = *reinterpret_cast<const f32x4*>(ed4 + (size_t)n * 4);
        f32x4 m    = (f32x4){-INFINITY, -INFINITY, -INFINITY, -INFINITY};
        f32x4 dsum = (f32x4){0.f, 0.f, 0.f, 0.f};
        f32x8 acc  = (f32x8){0.f, 0.f, 0.f, 0.f, 0.f, 0.f, 0.f, 0.f};
        for (int c0 = 0; c0 < deg; c0 += 64) {
            int cn = min(deg - c0, 64);
            f32x4 ev;
            if (l < cn) {
                int s = csr[base + c0 + l];
                s_lds[wv][l] = s;
                f32x4 e = *reinterpret_cast<const f32x4*>(es4 + (size_t)s * 4);
#pragma unroll
                for (int h = 0; h < 4; h++) {
                    float t = e[h] + edv[h];
                    ev[h] = (t > 0.f) ? t : 0.2f * t;
                }
            } else {
#pragma unroll
                for (int h = 0; h < 4; h++) ev[h] = -INFINITY;
            }
            f32x4 mc = ev;
#pragma unroll
            for (int o = 32; o; o >>= 1)
#pragma unroll
                for (int h = 0; h < 4; h++) mc[h] = fmaxf(mc[h], __shfl_xor(mc[h], o));
            f32x4 al, pv;
#pragma unroll
            for (int h = 0; h < 4; h++) {
                float nm = fmaxf(m[h], mc[h]);
                al[h] = __expf(m[h] - nm);
                m[h]  = nm;
            }
#pragma unroll
            for (int h = 0; h < 4; h++) pv[h] = (l < cn) ? __expf(ev[h] - m[h]) : 0.f;
            f32x4 sc = pv;
#pragma unroll
            for (int o = 32; o; o >>= 1)
#pragma unroll
                for (int h = 0; h < 4; h++) sc[h] += __shfl_xor(sc[h], o);
#pragma unroll
            for (int h = 0; h < 4; h++) dsum[h] = dsum[h] * al[h] + sc[h];
            float ah = al[hd8];
#pragma unroll
            for (int k = 0; k < 8; k++) acc[k] *= ah;
            *reinterpret_cast<f32x4*>(&p_lds[wv][l * 4]) = pv;
            // paired gather: 8 pairs (16 edges) per unrolled iteration
            for (int j0 = half; j0 < cn; j0 += 16) {
                int   idx[8];
                float pj[8];
#pragma unroll
                for (int i = 0; i < 8; i++) {
                    int e  = j0 + 2 * i;
                    int ec = min(e, cn - 1);
                    idx[i] = s_lds[wv][ec];
                    pj[i]  = (e < cn) ? p_lds[wv][ec * 4 + hd8] : 0.f;
                }
                s16x8 hv[8];
#pragma unroll
                for (int i = 0; i < 8; i++)
                    hv[i] = *reinterpret_cast<const s16x8*>(Hb + (size_t)idx[i] * HC + fl * 8);
#pragma unroll
                for (int i = 0; i < 8; i++)
#pragma unroll
                    for (int k = 0; k < 8; k++) acc[k] = fmaf(pj[i], bs2f(hv[i][k]), acc[k]);
            }
        }
        // merge the two edge-halves
#pragma unroll
        for (int k = 0; k < 8; k++) acc[k] += __shfl_xor(acc[k], 32);
        if (half == 0) {
            float dd = fmaxf(dsum[hd8], 1e-16f);
            s16x8 ov;
#pragma unroll
            for (int k = 0; k < 8; k++) {
                float v = acc[k] / dd + ldf(bias, (size_t)fl * 8 + k, bf);
                ov[k] = f2bs(fmaxf(v, 0.f));
            }
            *reinterpret_cast<s16x8*>(out + (size_t)n * HC + fl * 8) = ov;
        }
    }
}

// ---------------- readout ----------------
__global__ __launch_bounds__(256) void k_groupsum(const __hip_bfloat16* __restrict__ X2,
                                                  const int* __restrict__ batch,
                                                  const int* __restrict__ ei,
                                                  float* __restrict__ sx) {
    int f = probe_i64(ei);
    const int RPB = NNODES / 250;  // 80
    int b = blockIdx.x, t = threadIdx.x;
    int r0 = b * RPB, r1 = r0 + RPB;
    float acc = 0.f;
    int curg = ld_idx(batch, r0, f);
    for (int r = r0; r < r1; r++) {
        int g = ld_idx(batch, r, f);
        if (g != curg) { atomicAdd(&sx[(size_t)curg * HC + t], acc); acc = 0.f; curg = g; }
        acc += b2f(X2[(size_t)r * HC + t]);
    }
    atomicAdd(&sx[(size_t)curg * HC + t], acc);
}

__global__ __launch_bounds__(256) void k_final(const float* __restrict__ sx,
                                               const void* __restrict__ Wp,
                                               const void* __restrict__ bp,
                                               const int* __restrict__ batch,
                                               const int* __restrict__ ei,
                                               const void* __restrict__ xprobe,
                                               void* __restrict__ out) {
    int f  = probe_i64(ei);
    int bf = probe_bf((const unsigned int*)xprobe);
    int i = blockIdx.x * 256 + threadIdx.x;  // 2048 = 64*32
    int g = i >> 5, c = i & 31;
    int lo = 0, hi = NNODES;
    while (lo < hi) { int m = (lo + hi) >> 1; if (ld_idx(batch, m, f) < g) lo = m + 1; else hi = m; }
    int start = lo;
    hi = NNODES;
    while (lo < hi) { int m = (lo + hi) >> 1; if (ld_idx(batch, m, f) < g + 1) lo = m + 1; else hi = m; }
    int ct = lo - start;
    float acc = 0.f;
    const float* sxg = sx + (size_t)g * HC;
    for (int k = 0; k < HC; k++) acc = fmaf(sxg[k], ldf(Wp, (size_t)k * DOUT + c, bf), acc);
    float v = (ct > 0) ? (acc / ct + ldf(bp, c, bf)) : 0.f;
    if (bf) ((__hip_bfloat16*)out)[i] = __float2bfloat16(v);
    else    ((float*)out)[i] = v;
}

extern "C" void kernel_launch(void* const* d_in, const int* in_sizes, int n_in,
                              void* d_out, int out_size, void* d_ws, size_t ws_size,
                              hipStream_t stream) {
    (void)in_sizes; (void)n_in; (void)out_size; (void)ws_size;
    const void* x   = d_in[0];
    const int*  ei  = (const int*)d_in[1];
    const int*  bat = (const int*)d_in[2];
    const void* W1  = d_in[3];
    const void* as1 = d_in[4];
    const void* ad1 = d_in[5];
    const void* b1  = d_in[6];
    const void* W2  = d_in[7];
    const void* as2 = d_in[8];
    const void* ad2 = d_in[9];
    const void* b2  = d_in[10];
    const void* Wp  = d_in[11];
    const void* bp  = d_in[12];

    char* ws = (char*)d_ws;
    size_t o = 0;
    auto alloc = [&](size_t bytes) -> char* {
        char* p = ws + o;
        o += (bytes + 255) & ~(size_t)255;
        return p;
    };
    __hip_bfloat16* hb  = (__hip_bfloat16*)alloc((size_t)NNODES * HC * 2);
    __hip_bfloat16* xb  = (__hip_bfloat16*)alloc((size_t)NNODES * HC * 2);
    __hip_bfloat16* xb2 = (__hip_bfloat16*)alloc((size_t)NNODES * HC * 2);
    __hip_bfloat16* Wt1 = (__hip_bfloat16*)alloc((size_t)HC * HC * 2);
    __hip_bfloat16* Wt2 = (__hip_bfloat16*)alloc((size_t)HC * HC * 2);
    float* es = (float*)alloc((size_t)NNODES * 4 * 4);
    float* ed = (float*)alloc((size_t)NNODES * 4 * 4);
    int* deg  = (int*)alloc((size_t)NNODES * 4);
    int* cur  = (int*)alloc((size_t)NNODES * 4);
    int* off  = (int*)alloc((size_t)(NNODES + 1) * 4);
    int* csr  = (int*)alloc((size_t)ETOT * 4);
    float* sx = (float*)alloc((size_t)NGROUP * HC * 4);

    hipMemsetAsync(deg, 0, (size_t)NNODES * 4, stream);
    hipMemsetAsync(sx, 0, (size_t)NGROUP * HC * 4, stream);

    // CSR (shared by both layers)
    k_hist<<<(ETOT + 255) / 256, 256, 0, stream>>>(ei, deg);
    k_scan<<<1, 512, 0, stream>>>(deg, off, cur);
    k_scatter<<<(ETOT + 255) / 256, 256, 0, stream>>>(ei, cur, csr);
    k_wt<<<512, 256, 0, stream>>>(W1, W2, Wt1, Wt2);

    // Layer 1
    k_gemm<<<(NNODES + 63) / 64, 512, 0, stream>>>(x, Wt1, hb, as1, ad1, es, ed, x, 0);
    k_agg<<<1250, 256, 0, stream>>>(hb, es, ed, b1, off, csr, x, xb);

    // Layer 2
    k_gemm<<<(NNODES + 63) / 64, 512, 0, stream>>>(xb, Wt2, hb, as2, ad2, es, ed, x, 1);
    k_agg<<<1250, 256, 0, stream>>>(hb, es, ed, b2, off, csr, x, xb2);

    // Readout
    k_groupsum<<<250, 256, 0, stream>>>(xb2, bat, ei, sx);
    k_final<<<8, 256, 0, stream>>>(sx, Wp, bp, bat, ei, x, d_out);
}

// Round 8
// 402.950 us; speedup vs baseline: 1.0173x; 1.0173x over previous
//
#include <hip/hip_runtime.h>
#include <hip/hip_bf16.h>
#include <cstdint>

#define NNODES 20000
#define NEDGES 640000
#define ETOT   (NEDGES + NNODES)
#define NGROUP 64
#define HC     256
#define DOUT   32
#define SCAT_BLOCKS ((ETOT + 255) / 256)

typedef short bf16x8 __attribute__((ext_vector_type(8)));
typedef short s16x4  __attribute__((ext_vector_type(4)));
typedef float f32x4  __attribute__((ext_vector_type(4)));
typedef float f32x2  __attribute__((ext_vector_type(2)));

__device__ __forceinline__ float b2f(__hip_bfloat16 v) { return __bfloat162float(v); }
__device__ __forceinline__ float bs2f(short v) {
    union { unsigned int u; float f; } c; c.u = ((unsigned int)(unsigned short)v) << 16; return c.f;
}
__device__ __forceinline__ short f2bs(float v) {
    __hip_bfloat16 b = __float2bfloat16(v);
    union { __hip_bfloat16 b; short s; } u; u.b = b; return u.s;
}
__device__ __forceinline__ float ldf(const void* __restrict__ p, size_t i, int bf) {
    return bf ? __bfloat162float(((const __hip_bfloat16*)p)[i]) : ((const float*)p)[i];
}
__device__ __forceinline__ int ld_idx(const int* __restrict__ p, size_t i, int f64) {
    return f64 ? p[2 * i] : p[i];
}

// ---- inline wave probes (wave-uniform branch points only) ----
__device__ __forceinline__ int probe_i64(const int* __restrict__ ei) {
    int l = threadIdx.x & 63;
    unsigned long long b = __ballot(ei[2 * l + 1] == 0);
    return (__popcll(b) > 48) ? 1 : 0;
}
__device__ __forceinline__ int probe_bf(const unsigned int* __restrict__ xw) {
    int l = threadIdx.x & 63;
    unsigned long long b = __ballot((xw[l] >> 14) & 1);
    return (__popcll(b) < 16) ? 1 : 0;
}

// ---------------- CSR: histogram ----------------
__global__ void k_hist(const int* __restrict__ ei, int* __restrict__ deg) {
    int f = probe_i64(ei);
    int i = blockIdx.x * blockDim.x + threadIdx.x;
    if (i >= ETOT) return;
    int d = (i < NEDGES) ? ld_idx(ei, (size_t)NEDGES + i, f) : (i - NEDGES);
    atomicAdd(&deg[d], 1);
}

// ---------------- CSR: scan (single block) ----------------
__global__ void k_scan(const int* __restrict__ deg, int* __restrict__ off, int* __restrict__ cur) {
    __shared__ unsigned short dl[NNODES];  // 40 KB
    __shared__ int wtot[8];
    int t = threadIdx.x;
    for (int i = t; i < NNODES; i += 512) dl[i] = (unsigned short)deg[i];
    __syncthreads();
    const int chunk = (NNODES + 511) / 512;  // 40
    int s = t * chunk, e = min(s + chunk, NNODES);
    int sum = 0;
    for (int i = s; i < e; i++) sum += dl[i];
    int lane = t & 63, wv = t >> 6;
    int v = sum;
#pragma unroll
    for (int o = 1; o < 64; o <<= 1) {
        int u = __shfl_up(v, o);
        if (lane >= o) v += u;
    }
    if (lane == 63) wtot[wv] = v;
    __syncthreads();
    int woff = 0;
    for (int i = 0; i < wv; i++) woff += wtot[i];
    int run = woff + v - sum;
    for (int i = s; i < e; i++) { off[i] = run; cur[i] = run; run += dl[i]; }
    if (t == 511) off[NNODES] = ETOT;
}

// ---------------- CSR scatter + weight transposes (fused, block-range branch) ----------------
__global__ void k_scatter_wt(const int* __restrict__ ei, int* __restrict__ cur,
                             int* __restrict__ csr,
                             const void* __restrict__ W1, const void* __restrict__ W2,
                             __hip_bfloat16* __restrict__ Wt1, __hip_bfloat16* __restrict__ Wt2) {
    int b = blockIdx.x;
    if (b < SCAT_BLOCKS) {
        int f = probe_i64(ei);
        int i = b * 256 + threadIdx.x;
        if (i >= ETOT) return;
        int s, d;
        if (i < NEDGES) { s = ld_idx(ei, i, f); d = ld_idx(ei, (size_t)NEDGES + i, f); }
        else            { s = d = i - NEDGES; }
        int pos = atomicAdd(&cur[d], 1);
        csr[pos] = s;
    } else {
        int bf = probe_bf((const unsigned int*)W1);
        int i = (b - SCAT_BLOCKS) * 256 + threadIdx.x;  // 0..131071
        int which = i >> 16;
        int j = i & 65535;
        int k = j >> 8, n = j & 255;
        const void* W = which ? W2 : W1;
        __hip_bfloat16* Wt = which ? Wt2 : Wt1;
        Wt[(size_t)n * 256 + k] = __float2bfloat16(ldf(W, (size_t)k * 256 + n, bf));
    }
}

// ---------------- GEMM (64 rows/block, 8 waves of 512) + fused scores ----------------
// wave w: rows r0 = blk*64 + (w&3)*16, col-half ch = w>>2 (heads 2ch,2ch+1). acc[8].
// A frag: lane holds A[m=lane&15][k=(lane>>4)*8+j]; B mirrors with n=lane&15.
// D frag: col=lane&15, row=(lane>>4)*4+reg (m89/m91-verified).
__global__ __launch_bounds__(512) void k_gemm(const void* __restrict__ A,
                                              const __hip_bfloat16* __restrict__ Bt,
                                              __hip_bfloat16* __restrict__ Hout,
                                              const void* __restrict__ a_src,
                                              const void* __restrict__ a_dst,
                                              float* __restrict__ es4, float* __restrict__ ed4,
                                              const void* __restrict__ xprobe, int force_bf) {
    int bf   = probe_bf((const unsigned int*)xprobe);
    int abf  = force_bf | bf;
    int w    = threadIdx.x >> 6;
    int lane = threadIdx.x & 63;
    int mr   = lane & 15;
    int quad = lane >> 4;
    int ch   = w >> 2;
    int r0   = blockIdx.x * 64 + (w & 3) * 16;
    f32x4 acc[8];
#pragma unroll
    for (int j = 0; j < 8; j++) acc[j] = (f32x4){0.f, 0.f, 0.f, 0.f};
    size_t rowoff = (size_t)min(r0 + mr, NNODES - 1) * HC;
    for (int kk = 0; kk < HC; kk += 32) {
        bf16x8 a;
        if (abf) {
            a = *reinterpret_cast<const bf16x8*>((const __hip_bfloat16*)A + rowoff + kk + quad * 8);
        } else {
            const float* af = (const float*)A + rowoff + kk + quad * 8;
            f32x4 lo = *reinterpret_cast<const f32x4*>(af);
            f32x4 hi = *reinterpret_cast<const f32x4*>(af + 4);
#pragma unroll
            for (int ii = 0; ii < 4; ii++) { a[ii] = f2bs(lo[ii]); a[ii + 4] = f2bs(hi[ii]); }
        }
#pragma unroll
        for (int j = 0; j < 8; j++) {
            bf16x8 b = *reinterpret_cast<const bf16x8*>(
                Bt + (size_t)(ch * 128 + j * 16 + mr) * HC + kk + quad * 8);
            acc[j] = __builtin_amdgcn_mfma_f32_16x16x32_bf16(a, b, acc[j], 0, 0, 0);
        }
    }
#pragma unroll
    for (int j = 0; j < 8; j++)
#pragma unroll
        for (int r = 0; r < 4; r++) {
            int row = r0 + quad * 4 + r;
            if (row < NNODES)
                Hout[(size_t)row * HC + ch * 128 + j * 16 + mr] = __float2bfloat16(acc[j][r]);
        }
    float ps[2][4], pd[2][4];
#pragma unroll
    for (int h = 0; h < 2; h++)
#pragma unroll
        for (int r = 0; r < 4; r++) { ps[h][r] = 0.f; pd[h][r] = 0.f; }
#pragma unroll
    for (int j = 0; j < 8; j++) {
        int h = j >> 2;
        size_t col = (size_t)ch * 128 + j * 16 + mr;
        float asv = ldf(a_src, col, bf);
        float adv = ldf(a_dst, col, bf);
#pragma unroll
        for (int r = 0; r < 4; r++) {
            ps[h][r] = fmaf(acc[j][r], asv, ps[h][r]);
            pd[h][r] = fmaf(acc[j][r], adv, pd[h][r]);
        }
    }
#pragma unroll
    for (int o = 1; o < 16; o <<= 1)
#pragma unroll
        for (int h = 0; h < 2; h++)
#pragma unroll
            for (int r = 0; r < 4; r++) {
                ps[h][r] += __shfl_xor(ps[h][r], o);
                pd[h][r] += __shfl_xor(pd[h][r], o);
            }
    if (mr == 0)
#pragma unroll
        for (int r = 0; r < 4; r++) {
            int row = r0 + quad * 4 + r;
            if (row < NNODES) {
                *reinterpret_cast<f32x2*>(es4 + (size_t)row * 4 + ch * 2) = (f32x2){ps[0][r], ps[1][r]};
                *reinterpret_cast<f32x2*>(ed4 + (size_t)row * 4 + ch * 2) = (f32x2){pd[0][r], pd[1][r]};
            }
        }
}

// ---------------- wave-per-node softmax + aggregation (round-6 body, 5000 blocks) ----------------
// lane l owns features l*4..l*4+3 (head l>>4); edges in chunks of 64; gather 8-way unrolled.
__global__ __launch_bounds__(256) void k_agg(const __hip_bfloat16* __restrict__ Hb,
                                             const float* __restrict__ es4, const float* __restrict__ ed4,
                                             const void* __restrict__ bias,
                                             const int* __restrict__ off, const int* __restrict__ csr,
                                             const void* __restrict__ xprobe,
                                             __hip_bfloat16* __restrict__ out) {
    __shared__ float p_lds[4][256];
    __shared__ int   s_lds[4][64];
    int bf = probe_bf((const unsigned int*)xprobe);
    int wv = threadIdx.x >> 6;
    int l  = threadIdx.x & 63;
    int n  = blockIdx.x * 4 + wv;
    int hd = l >> 4;
    int base = off[n], deg = off[n + 1] - base;
    f32x4 edv = *reinterpret_cast<const f32x4*>(ed4 + (size_t)n * 4);
    f32x4 m    = (f32x4){-INFINITY, -INFINITY, -INFINITY, -INFINITY};
    f32x4 dsum = (f32x4){0.f, 0.f, 0.f, 0.f};
    f32x4 acc  = (f32x4){0.f, 0.f, 0.f, 0.f};
    for (int c0 = 0; c0 < deg; c0 += 64) {
        int cn = min(deg - c0, 64);
        f32x4 ev;
        if (l < cn) {
            int s = csr[base + c0 + l];
            s_lds[wv][l] = s;
            f32x4 e = *reinterpret_cast<const f32x4*>(es4 + (size_t)s * 4);
#pragma unroll
            for (int h = 0; h < 4; h++) {
                float t = e[h] + edv[h];
                ev[h] = (t > 0.f) ? t : 0.2f * t;
            }
        } else {
#pragma unroll
            for (int h = 0; h < 4; h++) ev[h] = -INFINITY;
        }
        f32x4 mc = ev;
#pragma unroll
        for (int o = 32; o; o >>= 1)
#pragma unroll
            for (int h = 0; h < 4; h++) mc[h] = fmaxf(mc[h], __shfl_xor(mc[h], o));
        f32x4 al, pv;
#pragma unroll
        for (int h = 0; h < 4; h++) {
            float nm = fmaxf(m[h], mc[h]);
            al[h] = __expf(m[h] - nm);
            m[h]  = nm;
        }
#pragma unroll
        for (int h = 0; h < 4; h++) pv[h] = (l < cn) ? __expf(ev[h] - m[h]) : 0.f;
        f32x4 sc = pv;
#pragma unroll
        for (int o = 32; o; o >>= 1)
#pragma unroll
            for (int h = 0; h < 4; h++) sc[h] += __shfl_xor(sc[h], o);
#pragma unroll
        for (int h = 0; h < 4; h++) dsum[h] = dsum[h] * al[h] + sc[h];
        acc *= al[hd];
        *reinterpret_cast<f32x4*>(&p_lds[wv][l * 4]) = pv;
        int jm = cn & ~7;
        for (int j = 0; j < jm; j += 8) {
            s16x4 hv[8];
            float pj[8];
#pragma unroll
            for (int i = 0; i < 8; i++) {
                int sj = s_lds[wv][j + i];
                hv[i] = *reinterpret_cast<const s16x4*>(Hb + (size_t)sj * HC + l * 4);
                pj[i] = p_lds[wv][(j + i) * 4 + hd];
            }
#pragma unroll
            for (int i = 0; i < 8; i++)
#pragma unroll
                for (int k = 0; k < 4; k++) acc[k] = fmaf(pj[i], bs2f(hv[i][k]), acc[k]);
        }
        for (int j = jm; j < cn; j++) {
            int sj  = s_lds[wv][j];
            float p = p_lds[wv][j * 4 + hd];
            s16x4 hv = *reinterpret_cast<const s16x4*>(Hb + (size_t)sj * HC + l * 4);
#pragma unroll
            for (int k = 0; k < 4; k++) acc[k] = fmaf(p, bs2f(hv[k]), acc[k]);
        }
    }
    float dd = fmaxf(dsum[hd], 1e-16f);
    s16x4 ov;
#pragma unroll
    for (int k = 0; k < 4; k++) {
        float v = acc[k] / dd + ldf(bias, (size_t)l * 4 + k, bf);
        ov[k] = f2bs(fmaxf(v, 0.f));
    }
    *reinterpret_cast<s16x4*>(out + (size_t)n * HC + l * 4) = ov;
}

// ---------------- readout ----------------
__global__ __launch_bounds__(256) void k_groupsum(const __hip_bfloat16* __restrict__ X2,
                                                  const int* __restrict__ batch,
                                                  const int* __restrict__ ei,
                                                  float* __restrict__ sx) {
    int f = probe_i64(ei);
    const int RPB = NNODES / 250;  // 80
    int b = blockIdx.x, t = threadIdx.x;
    int r0 = b * RPB, r1 = r0 + RPB;
    float acc = 0.f;
    int curg = ld_idx(batch, r0, f);
    for (int r = r0; r < r1; r++) {
        int g = ld_idx(batch, r, f);
        if (g != curg) { atomicAdd(&sx[(size_t)curg * HC + t], acc); acc = 0.f; curg = g; }
        acc += b2f(X2[(size_t)r * HC + t]);
    }
    atomicAdd(&sx[(size_t)curg * HC + t], acc);
}

__global__ __launch_bounds__(256) void k_final(const float* __restrict__ sx,
                                               const void* __restrict__ Wp,
                                               const void* __restrict__ bp,
                                               const int* __restrict__ batch,
                                               const int* __restrict__ ei,
                                               const void* __restrict__ xprobe,
                                               void* __restrict__ out) {
    int f  = probe_i64(ei);
    int bf = probe_bf((const unsigned int*)xprobe);
    int i = blockIdx.x * 256 + threadIdx.x;  // 2048 = 64*32
    int g = i >> 5, c = i & 31;
    int lo = 0, hi = NNODES;
    while (lo < hi) { int m = (lo + hi) >> 1; if (ld_idx(batch, m, f) < g) lo = m + 1; else hi = m; }
    int start = lo;
    hi = NNODES;
    while (lo < hi) { int m = (lo + hi) >> 1; if (ld_idx(batch, m, f) < g + 1) lo = m + 1; else hi = m; }
    int ct = lo - start;
    float acc = 0.f;
    const float* sxg = sx + (size_t)g * HC;
    for (int k = 0; k < HC; k++) acc = fmaf(sxg[k], ldf(Wp, (size_t)k * DOUT + c, bf), acc);
    float v = (ct > 0) ? (acc / ct + ldf(bp, c, bf)) : 0.f;
    if (bf) ((__hip_bfloat16*)out)[i] = __float2bfloat16(v);
    else    ((float*)out)[i] = v;
}

extern "C" void kernel_launch(void* const* d_in, const int* in_sizes, int n_in,
                              void* d_out, int out_size, void* d_ws, size_t ws_size,
                              hipStream_t stream) {
    (void)in_sizes; (void)n_in; (void)out_size; (void)ws_size;
    const void* x   = d_in[0];
    const int*  ei  = (const int*)d_in[1];
    const int*  bat = (const int*)d_in[2];
    const void* W1  = d_in[3];
    const void* as1 = d_in[4];
    const void* ad1 = d_in[5];
    const void* b1  = d_in[6];
    const void* W2  = d_in[7];
    const void* as2 = d_in[8];
    const void* ad2 = d_in[9];
    const void* b2  = d_in[10];
    const void* Wp  = d_in[11];
    const void* bp  = d_in[12];

    char* ws = (char*)d_ws;
    size_t o = 0;
    auto alloc = [&](size_t bytes) -> char* {
        char* p = ws + o;
        o += (bytes + 255) & ~(size_t)255;
        return p;
    };
    __hip_bfloat16* hb  = (__hip_bfloat16*)alloc((size_t)NNODES * HC * 2);
    __hip_bfloat16* xb  = (__hip_bfloat16*)alloc((size_t)NNODES * HC * 2);
    __hip_bfloat16* xb2 = (__hip_bfloat16*)alloc((size_t)NNODES * HC * 2);
    __hip_bfloat16* Wt1 = (__hip_bfloat16*)alloc((size_t)HC * HC * 2);
    __hip_bfloat16* Wt2 = (__hip_bfloat16*)alloc((size_t)HC * HC * 2);
    float* es = (float*)alloc((size_t)NNODES * 4 * 4);
    float* ed = (float*)alloc((size_t)NNODES * 4 * 4);
    // deg and sx adjacent -> one memset zeroes both
    char* zbase = alloc((size_t)NNODES * 4 + (size_t)NGROUP * HC * 4 + 256);
    int*   deg = (int*)zbase;
    float* sx  = (float*)(zbase + ((size_t)NNODES * 4 + 255 & ~(size_t)255));
    size_t zlen = ((size_t)NNODES * 4 + 255 & ~(size_t)255) + (size_t)NGROUP * HC * 4;
    int* cur  = (int*)alloc((size_t)NNODES * 4);
    int* off  = (int*)alloc((size_t)(NNODES + 1) * 4);
    int* csr  = (int*)alloc((size_t)ETOT * 4);

    hipMemsetAsync(zbase, 0, zlen, stream);

    // CSR (shared by both layers) + weight prep
    k_hist<<<(ETOT + 255) / 256, 256, 0, stream>>>(ei, deg);
    k_scan<<<1, 512, 0, stream>>>(deg, off, cur);
    k_scatter_wt<<<SCAT_BLOCKS + 512, 256, 0, stream>>>(ei, cur, csr, W1, W2, Wt1, Wt2);

    // Layer 1
    k_gemm<<<(NNODES + 63) / 64, 512, 0, stream>>>(x, Wt1, hb, as1, ad1, es, ed, x, 0);
    k_agg<<<NNODES / 4, 256, 0, stream>>>(hb, es, ed, b1, off, csr, x, xb);

    // Layer 2
    k_gemm<<<(NNODES + 63) / 64, 512, 0, stream>>>(xb, Wt2, hb, as2, ad2, es, ed, x, 1);
    k_agg<<<NNODES / 4, 256, 0, stream>>>(hb, es, ed, b2, off, csr, x, xb2);

    // Readout
    k_groupsum<<<250, 256, 0, stream>>>(xb2, bat, ei, sx);
    k_final<<<8, 256, 0, stream>>>(sx, Wp, bp, bat, ei, x, d_out);
}